// Round 6
// baseline (385.505 us; speedup 1.0000x reference)
//
#include <hip/hip_runtime.h>
#include <math.h>

#define B 16
#define C 256
#define H 128
#define W 128
#define HW (H * W)      // 16384
#define HW4 (HW / 4)    // 4096 float4 chunks per image plane
#define W4 (W / 4)      // 32 float4 chunks per row

typedef float vfloat4 __attribute__((ext_vector_type(4)));

// ---------------------------------------------------------------------------
// FUSED kernel: channel mean/max reduction + 3x3 conv + sigmoid in ONE
// dispatch. Rationale (rounds 0-4): the reduce was invariant to nt/cached,
// 1KiB/4KiB granularity, and a 2x CU-work probe -> not CU-bound, and likely
// not even the dominant cost; best-fit decomposition says ~6 graph nodes x
// 10-15us dispatch overhead + the 161us harness ws-poison fill dominate.
// Fusing kills one node and the feat round-trip through d_ws.
//
// Partition: block = (image b, 8-row slab). It reduces C=256 channels over
// its slab + 1-row halo (rows [r0-1, r0+8] clamped; halo rows re-reduced by
// the neighbor block too -> 1.25x read redundancy, +67MB). Per channel step
// a wave reads the whole 9/10-row span = up to 5 KiB CONTIGUOUS. 8 waves
// split channels (32 each); LDS combine; conv reads the feat tile from LDS
// with zero-padding at image borders; sigmoid; write 8 output rows.
// Grid 256 blocks x 512 threads = the round-3 proven-BW geometry.
// ---------------------------------------------------------------------------
__global__ __launch_bounds__(512) void fused_mean_max_conv(
    const float* __restrict__ x, const float* __restrict__ wgt,
    float* __restrict__ out) {
  const int t    = threadIdx.x;
  const int lane = t & 63;
  const int wv   = t >> 6;                    // wave id 0..7 = channel group
  const int b    = blockIdx.x >> 4;           // image
  const int r0   = (blockIdx.x & 15) << 3;    // first output row of slab
  const int rlo  = (r0 == 0) ? 0 : r0 - 1;    // first tile row (w/ halo)
  const int rhi  = (r0 == 120) ? 127 : r0 + 8;// last tile row  (w/ halo)
  const int nchunks = (rhi - rlo + 1) * W4;   // 288 or 320 float4 chunks

  __shared__ float   sw[18];                  // conv weights
  __shared__ vfloat4 s_buf[8][320];           // 40 KiB partials, reused twice
  __shared__ float   fmean[1280];             // 10 rows x 128
  __shared__ float   fmaxv[1280];

  if (t < 18) sw[t] = wgt[t];

  // ---- phase 1: per-wave channel reduction over the tile ----
  const vfloat4* xp = (const vfloat4*)x +
      (size_t)(b * C + wv * 32) * HW4 + rlo * W4;

  vfloat4 sum[5], mx[5];
#pragma unroll
  for (int i = 0; i < 5; ++i) {
    sum[i] = (vfloat4)(0.f);
    mx[i]  = (vfloat4)(-INFINITY);
  }

#pragma unroll 4
  for (int c = 0; c < 32; ++c) {
    const vfloat4* p = xp + (size_t)c * HW4;  // one channel plane
#pragma unroll
    for (int i = 0; i < 5; ++i) {             // up to 5 KiB contiguous/wave
      const int j = i * 64 + lane;
      if (j < nchunks) {                      // only i==4 can fail (edges)
        vfloat4 v = p[j];
        sum[i] += v;
        mx[i].x = fmaxf(mx[i].x, v.x);
        mx[i].y = fmaxf(mx[i].y, v.y);
        mx[i].z = fmaxf(mx[i].z, v.z);
        mx[i].w = fmaxf(mx[i].w, v.w);
      }
    }
  }

  // ---- phase 2: cross-wave combine (sum pass, then max pass) ----
#pragma unroll
  for (int i = 0; i < 5; ++i) s_buf[wv][i * 64 + lane] = sum[i];
  __syncthreads();
  if (t < nchunks) {
    vfloat4 a = (vfloat4)(0.f);
#pragma unroll
    for (int w2 = 0; w2 < 8; ++w2) a += s_buf[w2][t];
    ((vfloat4*)fmean)[t] = a * (1.0f / (float)C);
  }
  __syncthreads();
#pragma unroll
  for (int i = 0; i < 5; ++i) s_buf[wv][i * 64 + lane] = mx[i];
  __syncthreads();
  if (t < nchunks) {
    vfloat4 m = s_buf[0][t];
#pragma unroll
    for (int w2 = 1; w2 < 8; ++w2) {
      vfloat4 v = s_buf[w2][t];
      m.x = fmaxf(m.x, v.x);
      m.y = fmaxf(m.y, v.y);
      m.z = fmaxf(m.z, v.z);
      m.w = fmaxf(m.w, v.w);
    }
    ((vfloat4*)fmaxv)[t] = m;
  }
  __syncthreads();

  // ---- phase 3: 3x3 conv (zero pad) + sigmoid, 1024 outputs / block ----
#pragma unroll
  for (int oo = 0; oo < 2; ++oo) {
    const int o  = t + oo * 512;              // [0, 1024)
    const int ro = o >> 7;                    // output row in slab, 0..7
    const int w  = o & (W - 1);
    const int r  = r0 + ro;                   // global row

    float acc = 0.f;
#pragma unroll
    for (int ci = 0; ci < 2; ++ci) {
      const float* f  = ci ? fmaxv : fmean;
      const float* kw = sw + ci * 9;
#pragma unroll
      for (int dh = -1; dh <= 1; ++dh) {
        const int rr = r + dh;
        if (rr < 0 || rr >= H) continue;      // zero pad
        const float* frow = f + (rr - rlo) * W;
#pragma unroll
        for (int dw = -1; dw <= 1; ++dw) {
          const int ww = w + dw;
          if (ww < 0 || ww >= W) continue;    // zero pad
          acc += frow[ww] * kw[(dh + 1) * 3 + (dw + 1)];
        }
      }
    }
    out[(size_t)b * HW + r0 * W + o] = 1.f / (1.f + __expf(-acc));
  }
}

extern "C" void kernel_launch(void* const* d_in, const int* in_sizes, int n_in,
                              void* d_out, int out_size, void* d_ws, size_t ws_size,
                              hipStream_t stream) {
  const float* x   = (const float*)d_in[0];   // [16, 256, 128, 128] fp32
  const float* wgt = (const float*)d_in[1];   // [1, 2, 3, 3] fp32
  float* out = (float*)d_out;                 // [16, 1, 128, 128] fp32
  (void)d_ws; (void)ws_size;                  // workspace no longer used

  // 16 images x 16 slabs of 8 rows; single fused dispatch
  fused_mean_max_conv<<<256, 512, 0, stream>>>(x, wgt, out);
}